// Round 1
// baseline (1054.176 us; speedup 1.0000x reference)
//
#include <hip/hip_runtime.h>
#include <hip/hip_bf16.h>
#include <cstdint>

// Problem constants
#define NB    64     // batch
#define SEQ   4096   // TK
#define HID   512    // HID2
#define PROJ_ 256    // PROJ

typedef __attribute__((ext_vector_type(8))) short bf16x8;   // 8 bf16 = 4 VGPRs
typedef __attribute__((ext_vector_type(4))) float floatx4;  // MFMA acc

__device__ __forceinline__ unsigned short f2bf(float f) {
    // round-to-nearest-even f32 -> bf16 (no NaN handling needed; inputs finite)
    union { float f; unsigned u; } v; v.f = f;
    unsigned r = v.u + 0x7FFFu + ((v.u >> 16) & 1u);
    return (unsigned short)(r >> 16);
}

__device__ __forceinline__ float fast_tanh(float x) {
    // tanh(x) = (e^{2x}-1)/(e^{2x}+1); clamp so __expf never overflows
    x = fminf(15.f, fmaxf(-15.f, x));
    float e = __expf(2.f * x);
    return (e - 1.f) / (e + 1.f);
}

// ---------------------------------------------------------------------------
// Kernel 1: convert W_k (f32, [PROJ][HID]) to bf16 in workspace
__global__ __launch_bounds__(256) void wconv_kernel(
    const float* __restrict__ Wk, unsigned short* __restrict__ Wb)
{
    int i = blockIdx.x * 256 + threadIdx.x;  // grid covers PROJ_*HID exactly
    Wb[i] = f2bf(Wk[i]);
}

// ---------------------------------------------------------------------------
// Kernel 2: q[b][p] = sum_d query[b][d] * Wq[p][d]   (64 blocks, 256 thr)
__global__ __launch_bounds__(256) void qproj_kernel(
    const float* __restrict__ query, const float* __restrict__ Wq,
    float* __restrict__ qbuf)
{
    __shared__ float sq[HID];
    const int b = blockIdx.x;
    for (int i = threadIdx.x; i < HID; i += 256) sq[i] = query[b * HID + i];
    __syncthreads();
    const int p = threadIdx.x;
    const float4* w = (const float4*)(Wq + p * HID);
    float acc = 0.f;
    #pragma unroll 4
    for (int i = 0; i < HID / 4; ++i) {
        float4 wv = w[i];
        acc += wv.x * sq[4*i] + wv.y * sq[4*i+1] + wv.z * sq[4*i+2] + wv.w * sq[4*i+3];
    }
    qbuf[b * PROJ_ + p] = acc;
}

// ---------------------------------------------------------------------------
// Kernel 3 (dominant): fused  scores[b][s] = sum_p tanh(q[b][p] + key[b][s]·Wk[p]) * V[p]
// MFMA GEMM tile: BM=64 (s) x BN=256 (all p) x BK=32, 4 waves, 16x16x32 bf16.
// Fragment layouts per verified m89/m91 mapping:
//   A/B operand: lane holds row (lane&15), k = (lane>>4)*8 + j  (8 contiguous)
//   C/D:         col = lane&15, row = (lane>>4)*4 + reg
constexpr int BM   = 64;
constexpr int BK   = 32;
constexpr int LSTR = 40;   // LDS row stride (bf16 elems): 80B -> 16B-aligned, 2-way-only bank aliasing

__global__ __launch_bounds__(256, 3) void scores_kernel(
    const float* __restrict__ key,            // [NB][SEQ][HID] f32
    const unsigned short* __restrict__ Wb,    // [PROJ_][HID] bf16
    const float* __restrict__ qbuf,           // [NB][PROJ_]
    const float* __restrict__ Vv,             // [PROJ_]
    float* __restrict__ scores)               // [NB][SEQ]
{
    __shared__ __align__(16) unsigned short sA[BM * LSTR];      // 5 KB
    __shared__ __align__(16) unsigned short sB[PROJ_ * LSTR];   // 20 KB
    __shared__ float sRed[4][BM];                               // 1 KB

    const int b    = blockIdx.y;
    const int s0   = blockIdx.x * BM;
    const int tid  = threadIdx.x;
    const int wave = tid >> 6;
    const int lane = tid & 63;
    const int l15  = lane & 15;
    const int quad = lane >> 4;

    // Staging assignment: 8 threads/row, 32 rows/pass (rows of 32 elems)
    const int krow = tid >> 3;   // 0..31
    const int kcol = tid & 7;    // float4 / ushort4 column index
    const float* keyBase = key + (size_t)(b * SEQ + s0) * HID;

    floatx4 acc[4][4];
    #pragma unroll
    for (int mi = 0; mi < 4; ++mi)
        #pragma unroll
        for (int ni = 0; ni < 4; ++ni)
            acc[mi][ni] = (floatx4){0.f, 0.f, 0.f, 0.f};

    float4  kv0, kv1;
    ushort4 wv[8];

    // prefetch chunk 0
    kv0 = *(const float4*)(keyBase + krow * HID + kcol * 4);
    kv1 = *(const float4*)(keyBase + (krow + 32) * HID + kcol * 4);
    #pragma unroll
    for (int ps = 0; ps < 8; ++ps)
        wv[ps] = *(const ushort4*)(Wb + (ps * 32 + krow) * HID + kcol * 4);

    for (int kc = 0; kc < HID / BK; ++kc) {
        __syncthreads();   // previous iteration's frag reads done
        // cvt + store staged chunk to LDS
        {
            ushort4 c;
            c.x = f2bf(kv0.x); c.y = f2bf(kv0.y); c.z = f2bf(kv0.z); c.w = f2bf(kv0.w);
            *(ushort4*)&sA[krow * LSTR + kcol * 4] = c;
            c.x = f2bf(kv1.x); c.y = f2bf(kv1.y); c.z = f2bf(kv1.z); c.w = f2bf(kv1.w);
            *(ushort4*)&sA[(krow + 32) * LSTR + kcol * 4] = c;
            #pragma unroll
            for (int ps = 0; ps < 8; ++ps)
                *(ushort4*)&sB[(ps * 32 + krow) * LSTR + kcol * 4] = wv[ps];
        }
        __syncthreads();
        // prefetch next chunk (overlaps with MFMA below)
        if (kc + 1 < HID / BK) {
            const int d0 = (kc + 1) * BK;
            kv0 = *(const float4*)(keyBase + krow * HID + d0 + kcol * 4);
            kv1 = *(const float4*)(keyBase + (krow + 32) * HID + d0 + kcol * 4);
            #pragma unroll
            for (int ps = 0; ps < 8; ++ps)
                wv[ps] = *(const ushort4*)(Wb + (ps * 32 + krow) * HID + d0 + kcol * 4);
        }
        // LDS -> fragments -> MFMA
        bf16x8 af[4], bf[4];
        #pragma unroll
        for (int mi = 0; mi < 4; ++mi)
            af[mi] = *(const bf16x8*)&sA[(mi * 16 + l15) * LSTR + quad * 8];
        #pragma unroll
        for (int ni = 0; ni < 4; ++ni)
            bf[ni] = *(const bf16x8*)&sB[(wave * 64 + ni * 16 + l15) * LSTR + quad * 8];
        #pragma unroll
        for (int mi = 0; mi < 4; ++mi)
            #pragma unroll
            for (int ni = 0; ni < 4; ++ni)
                acc[mi][ni] = __builtin_amdgcn_mfma_f32_16x16x32_bf16(
                    af[mi], bf[ni], acc[mi][ni], 0, 0, 0);
    }

    // Epilogue: tanh(q + C) * V, reduce over p (cols), then across waves
    float red[4][4];
    #pragma unroll
    for (int mi = 0; mi < 4; ++mi)
        #pragma unroll
        for (int r = 0; r < 4; ++r)
            red[mi][r] = 0.f;

    #pragma unroll
    for (int ni = 0; ni < 4; ++ni) {
        const int p = wave * 64 + ni * 16 + l15;   // C/D col = lane&15
        const float qv = qbuf[b * PROJ_ + p];
        const float vv = Vv[p];
        #pragma unroll
        for (int mi = 0; mi < 4; ++mi)
            #pragma unroll
            for (int r = 0; r < 4; ++r)
                red[mi][r] += fast_tanh(qv + acc[mi][ni][r]) * vv;
    }
    // butterfly over the 16-lane column group (same s, 16 different p)
    #pragma unroll
    for (int mi = 0; mi < 4; ++mi)
        #pragma unroll
        for (int r = 0; r < 4; ++r) {
            float v = red[mi][r];
            v += __shfl_xor(v, 1);
            v += __shfl_xor(v, 2);
            v += __shfl_xor(v, 4);
            v += __shfl_xor(v, 8);
            if (l15 == 0) sRed[wave][mi * 16 + quad * 4 + r] = v;  // C/D row = quad*4+reg
        }
    __syncthreads();
    if (tid < BM) {
        float s = sRed[0][tid] + sRed[1][tid] + sRed[2][tid] + sRed[3][tid];
        scores[(size_t)b * SEQ + s0 + tid] = s;
    }
}

// ---------------------------------------------------------------------------
// Kernel 4: softmax over SEQ per batch -> attn output (f32)
__global__ __launch_bounds__(256) void softmax_kernel(
    const float* __restrict__ scores, float* __restrict__ attn)
{
    const int b = blockIdx.x, tid = threadIdx.x;
    const float* row = scores + (size_t)b * SEQ;
    float x[16];
    float m = -1e30f;
    #pragma unroll
    for (int i = 0; i < 16; ++i) { x[i] = row[i * 256 + tid]; m = fmaxf(m, x[i]); }
    #pragma unroll
    for (int off = 32; off; off >>= 1) m = fmaxf(m, __shfl_xor(m, off));
    __shared__ float sm[4];
    if ((tid & 63) == 0) sm[tid >> 6] = m;
    __syncthreads();
    m = fmaxf(fmaxf(sm[0], sm[1]), fmaxf(sm[2], sm[3]));
    float sum = 0.f;
    #pragma unroll
    for (int i = 0; i < 16; ++i) { x[i] = __expf(x[i] - m); sum += x[i]; }
    #pragma unroll
    for (int off = 32; off; off >>= 1) sum += __shfl_xor(sum, off);
    __shared__ float ss[4];
    if ((tid & 63) == 0) ss[tid >> 6] = sum;
    __syncthreads();
    const float inv = 1.0f / (ss[0] + ss[1] + ss[2] + ss[3]);
    #pragma unroll
    for (int i = 0; i < 16; ++i) attn[(size_t)b * SEQ + i * 256 + tid] = x[i] * inv;
}

// ---------------------------------------------------------------------------
// Kernel 5: out[b][d] = sum_s attn[b][s] * value[b][s][d]  (streams value)
constexpr int SCHUNK = 512;
__global__ __launch_bounds__(256) void outmv_kernel(
    const float* __restrict__ attn, const float* __restrict__ value,
    float* __restrict__ out)
{
    __shared__ float sw[SCHUNK];
    const int b   = blockIdx.y;
    const int sc  = blockIdx.x * SCHUNK;
    const int tid = threadIdx.x;
    for (int i = tid; i < SCHUNK; i += 256) sw[i] = attn[(size_t)b * SEQ + sc + i];
    __syncthreads();
    const float* vbase = value + (size_t)(b * SEQ + sc) * HID;
    float a0 = 0.f, a1 = 0.f;
    #pragma unroll 8
    for (int s = 0; s < SCHUNK; ++s) {
        const float w = sw[s];
        a0 += w * vbase[s * HID + tid];
        a1 += w * vbase[s * HID + tid + 256];
    }
    atomicAdd(&out[b * HID + tid], a0);
    atomicAdd(&out[b * HID + tid + 256], a1);
}

// ---------------------------------------------------------------------------
extern "C" void kernel_launch(void* const* d_in, const int* in_sizes, int n_in,
                              void* d_out, int out_size, void* d_ws, size_t ws_size,
                              hipStream_t stream) {
    const float* query = (const float*)d_in[0];  // [64][1][512]
    const float* key   = (const float*)d_in[1];  // [64][4096][512]
    const float* value = (const float*)d_in[2];  // [64][4096][512]
    const float* Wq    = (const float*)d_in[3];  // [256][512]
    const float* Wk    = (const float*)d_in[4];  // [256][512]
    const float* Vv    = (const float*)d_in[5];  // [1][256]

    float* out  = (float*)d_out;        // [64][512]
    float* attn = out + NB * HID;       // [64][4096]

    // workspace layout (needs 1.38 MB)
    float* scores        = (float*)d_ws;                         // NB*SEQ f32
    float* qbuf          = scores + NB * SEQ;                    // NB*PROJ_ f32
    unsigned short* Wb   = (unsigned short*)(qbuf + NB * PROJ_); // PROJ_*HID bf16

    hipMemsetAsync(out, 0, NB * HID * sizeof(float), stream);    // atomic accum target
    wconv_kernel<<<PROJ_ * HID / 256, 256, 0, stream>>>(Wk, Wb);
    qproj_kernel<<<NB, 256, 0, stream>>>(query, Wq, qbuf);
    scores_kernel<<<dim3(SEQ / BM, NB), 256, 0, stream>>>(key, Wb, qbuf, Vv, scores);
    softmax_kernel<<<NB, 256, 0, stream>>>(scores, attn);
    outmv_kernel<<<dim3(SEQ / SCHUNK, NB), 256, 0, stream>>>(attn, value, out);
}